// Round 8
// baseline (814.845 us; speedup 1.0000x reference)
//
#include <hip/hip_runtime.h>

// ClusterDiceLoss: segmented dice over 64 clusters of a 256^3 volume.
// 201 MB read-only. R3..R10: nine structures, all 72-81 us. Invariant to:
//   LDS layout/atomics/DS-op count, global-atomic contention, forced 24-deep
//   load pipeline, channel block-phasing, occupancy 27->64% (R10: doubled
//   occupancy, VGPR 20, time unchanged -> per-wave MLP branch dead).
//   Warm L3-resident replays == cold HBM runs (73.1 == 73.3) -> refutes
//   MSHR-x-latency; R6 (2x DS ops, same time) weakens DS-scatter floor.
// Last untested invariant: every round issued p4[idx], t4[idx], l4[idx]
//   SIMULTANEOUSLY -- three addresses exactly 64 MiB apart == same residue
//   at every pow2 hash level (HBM channel, L2 bank, L3 bank). 3-way
//   self-aliasing of each wave's instantaneous request set. Explains
//   warm==cold (L3 banks hash like channels) and R2's stride catastrophe.
// R11: (1) stream-disjoint stagger: T/L run 2 groups ahead; P[g] issues only
//   AFTER T[g],L[g] completed (verified vmcnt schedule below) -> the three
//   streams are never co-resident on one page. (2) finalize fused into
//   seg_count via last-block ticket (device-scope atomics + threadfence);
//   one less launch in the measured stream.

#define NSEG 65          // clusters 0..64 (0 = background, dropped)
#define NREP 64          // replicated global partial slots
#define REP_MASK 63
#define NCOPY 16         // LDS histogram copies (one per 16 lanes)
#define BLOCKS 4096
#define THREADS 256
#define GP 4             // float4-groups per thread (chunk = 1024)

typedef float4 f4;
typedef int4 i4;

// one 16-B load, 32-bit voffset + 64-bit SGPR base; volatile => pinned.
#define GLOAD(dst, voff, base) \
    asm volatile("global_load_dwordx4 %0, %1, %2" \
                 : "=v"(dst) : "v"(voff), "s"(base))

// wait for all but the newest NSTR outstanding loads; fence scheduler (rule 18)
#define WAITN(NSTR) do { \
    asm volatile("s_waitcnt vmcnt(" NSTR ")" ::: "memory"); \
    __builtin_amdgcn_sched_barrier(0); \
} while (0)

// Per-element u32 contribution: inter<<20 | sp<<10 | st.
// Bounds per LDS copy: 16 lanes x 16 elems = 256 max < 1023. Safe.
__device__ __forceinline__ unsigned int pack32(float p, float t) {
    unsigned int sp = (p != 0.0f) ? 1u : 0u;
    unsigned int st = (t != 0.0f) ? 1u : 0u;
    return ((sp & st) << 20) | (sp << 10) | st;
}

__device__ __forceinline__ void accum4(unsigned int (*s_cnt)[NSEG], int copy,
                                       f4 p, f4 t, i4 l) {
    atomicAdd(&s_cnt[copy][l.x], pack32(p.x, t.x));
    atomicAdd(&s_cnt[copy][l.y], pack32(p.y, t.y));
    atomicAdd(&s_cnt[copy][l.z], pack32(p.z, t.z));
    atomicAdd(&s_cnt[copy][l.w], pack32(p.w, t.w));
}

__global__ __launch_bounds__(THREADS, 4) void seg_count_fused_kernel(
    const float* __restrict__ pred,
    const float* __restrict__ target,
    const int* __restrict__ labels,
    unsigned long long* __restrict__ part,   // [NSEG][NREP] packed u64, zeroed
    unsigned int* __restrict__ ticket,       // zeroed
    const int* __restrict__ nc_ptr,
    float* __restrict__ out,
    int n)
{
    __shared__ unsigned int s_cnt[NCOPY][NSEG];   // 4160 B
    __shared__ float s_dice[64];
    __shared__ unsigned int s_last;
    const int tid = threadIdx.x;
    const int copy = tid >> 4;
    const int rep = (int)blockIdx.x & REP_MASK;

    for (int i = tid; i < NCOPY * NSEG; i += THREADS)
        ((unsigned int*)s_cnt)[i] = 0u;
    __syncthreads();

    const int n_vec = n >> 2;  // float4 groups
    const int chunk = (n_vec + (int)gridDim.x - 1) / (int)gridDim.x;
    const int base = blockIdx.x * chunk;
    const int end = min(base + chunk, n_vec);

    if (end - base == GP * THREADS) {
        // Stream-disjoint stagger. group g at byte offset vb + g*4096.
        // Outstanding-count audit (issue order left->right):
        //   T0 L0 T1 L1 | W2 -> {T1,L1}            (T0,L0 done)
        //   P0 T2 L2    | W2 -> {T2,L2}            (T1,L1,P0 done) accum g0
        //   P1 T3 L3    | W2 -> {T3,L3}            (T2,L2,P1 done) accum g1
        //   P2          | W1 -> {P2}               (T3,L3 done)
        //   P3          | W1 -> {P3}               (P2 done)       accum g2
        //               | W0 -> {}                 (P3 done)       accum g3
        // Invariant: P[g] is issued only after T[g],L[g] completed ->
        // pred never shares an in-flight page set with target/labels.
        const unsigned int vb = (unsigned int)(base + tid) * 16u;
        f4 P0, P1, P2, P3, T0, T1, T2, T3;
        i4 L0, L1, L2, L3;

        GLOAD(T0, vb,           target);
        GLOAD(L0, vb,           labels);
        GLOAD(T1, vb + 4096u,   target);
        GLOAD(L1, vb + 4096u,   labels);
        WAITN("2");
        GLOAD(P0, vb,           pred);
        GLOAD(T2, vb + 8192u,   target);
        GLOAD(L2, vb + 8192u,   labels);
        WAITN("2");
        accum4(s_cnt, copy, P0, T0, L0);
        GLOAD(P1, vb + 4096u,   pred);
        GLOAD(T3, vb + 12288u,  target);
        GLOAD(L3, vb + 12288u,  labels);
        WAITN("2");
        accum4(s_cnt, copy, P1, T1, L1);
        GLOAD(P2, vb + 8192u,   pred);
        WAITN("1");
        GLOAD(P3, vb + 12288u,  pred);
        WAITN("1");
        accum4(s_cnt, copy, P2, T2, L2);
        WAITN("0");
        accum4(s_cnt, copy, P3, T3, L3);
    } else {
        // generic fallback (not hit at n = 256^3 / 4096 blocks)
        const f4* __restrict__ p4 = (const f4*)pred;
        const f4* __restrict__ t4 = (const f4*)target;
        const i4* __restrict__ l4 = (const i4*)labels;
        for (int idx = base + tid; idx < end; idx += THREADS)
            accum4(s_cnt, copy, p4[idx], t4[idx], l4[idx]);
    }

    // scalar tail (n not divisible by 4): block 0 only
    if (blockIdx.x == 0) {
        for (int i = (n_vec << 2) + tid; i < n; i += THREADS)
            atomicAdd(&s_cnt[copy][labels[i]], pack32(pred[i], target[i]));
    }
    __syncthreads();

    // fold 16 u32 copies -> one packed u64 global atomic per segment.
    // Per-replica field bound: 64 blocks x 4096 = 262k < 2^21. Safe.
    for (int s = tid; s < NSEG; s += THREADS) {
        unsigned long long in = 0, sp = 0, st = 0;
        #pragma unroll
        for (int c = 0; c < NCOPY; ++c) {
            unsigned int v = s_cnt[c][s];
            st += v & 0x3FFu;
            sp += (v >> 10) & 0x3FFu;
            in += v >> 20;
        }
        unsigned long long tot = (in << 42) | (sp << 21) | st;
        if (tot) atomicAdd(&part[s * NREP + rep], tot);
    }

    // ---- last-block finalize (replaces the second launch) ----
    __threadfence();                 // publish this block's part[] atomics
    __syncthreads();
    if (tid == 0)
        s_last = (atomicAdd(ticket, 1u) == (unsigned int)gridDim.x - 1u) ? 1u : 0u;
    __syncthreads();
    if (s_last) {
        __threadfence();             // acquire side
        const int nc = *nc_ptr;      // 64
        const int s = 1 + (tid >> 2);
        const int q = tid & 3;
        unsigned long long acc = 0;
        unsigned long long* row = part + s * NREP + q * 16;
        #pragma unroll
        for (int i = 0; i < 16; ++i)
            acc += atomicAdd(&row[i], 0ull);   // device-scope coherent read
        acc += __shfl_xor(acc, 1);
        acc += __shfl_xor(acc, 2);
        if (q == 0) {
            float in = (float)(acc >> 42);
            float sp = (float)((acc >> 21) & 0x1FFFFFull);
            float st = (float)(acc & 0x1FFFFFull);
            float uni = sp + st;
            float dice = (uni > 0.0f) ? (2.0f * in / uni) : 1.0f;
            s_dice[s - 1] = (s <= nc) ? dice : 0.0f;
        }
        __syncthreads();
        if (tid < 64) {
            float local = s_dice[tid];
            #pragma unroll
            for (int off = 32; off > 0; off >>= 1)
                local += __shfl_down(local, off);
            if (tid == 0) out[0] = 1.0f - local / (float)nc;
        }
    }
}

extern "C" void kernel_launch(void* const* d_in, const int* in_sizes, int n_in,
                              void* d_out, int out_size, void* d_ws, size_t ws_size,
                              hipStream_t stream) {
    const float* pred   = (const float*)d_in[0];
    const float* target = (const float*)d_in[1];
    const int*   labels = (const int*)d_in[2];
    const int*   nc_ptr = (const int*)d_in[3];
    float* out = (float*)d_out;
    unsigned long long* part = (unsigned long long*)d_ws;
    unsigned int* ticket = (unsigned int*)((char*)d_ws + NSEG * NREP * 8);

    const int n = in_sizes[0];

    hipMemsetAsync(d_ws, 0, NSEG * NREP * 8 + 16, stream);

    seg_count_fused_kernel<<<BLOCKS, THREADS, 0, stream>>>(
        pred, target, labels, part, ticket, nc_ptr, out, n);
}

// Round 9
// 200.292 us; speedup vs baseline: 4.0683x; 4.0683x over previous
//
#include <hip/hip_runtime.h>

// ClusterDiceLoss: segmented dice over 64 clusters of a 256^3 volume.
// 201 MB read-only. R3..R10: nine structures, all 72-81 us (best R5 72.8 =
//   2.77 TB/s delivered). Invariant to LDS layout/atomics, global-atomic
//   contention, MLP depth 2..24, occupancy 27..80%, block channel-phase,
//   warm-vs-cold (L3-resident == HBM-fed).
// R11 (698 us, 9.5x REGRESSION): staggered streams by waiting for completion
//   -> destroyed MLP (VALUBusy 1%). Invalid test of aliasing; reverted.
// Remaining gap to known-good: m13 copy proves the read path sustains
//   >= 3.15 TB/s; we sit at 88%. The one difference: we read THREE streams
//   at exact 64-MiB offsets == same residue in every pow2 hash bit (L2
//   bank / L3 slice / channel), all waves in lockstep -> 3-way instantaneous
//   bank concentration. Fits warm==cold and R9's null.
// R12: valid de-alias at CONSTANT MLP. Per thread: L leads 3 groups, T 2,
//   P 1 -> in-flight set always spans 3 distinct 4-KB pages. Rotating NAMED
//   register FIFO (P:2, T:3, L:4 -- static unroll, never moves an in-flight
//   reg). Counted vmcnt(3), never drained mid-loop:
//   prologue: L0 L1 T0 L2 T1 P0                      (6 in flight)
//   g: issue L[g+3],T[g+2],P[g+1]; WAITN(3); accum(P[g],T[g],L[g])
//   (newer-than-P[g] = exactly the 3 just issued -> WAITN(3) is exact;
//    tail: WAITN(2)/(1)/(0) as issues cease.)
//   Accum/fold/finalize = proven-best R5/R10 structure (16-copy u32 LDS
//   atomics, 64-replica global slots, separate finalize kernel).

#define NSEG 65          // clusters 0..64 (0 = background, dropped)
#define NREP 64          // replicated global partial slots
#define REP_MASK 63
#define NCOPY 16         // LDS histogram copies (one per 16 lanes)
#define BLOCKS 2048
#define THREADS 256
#define GP 8             // float4-groups per thread (chunk = 2048)

typedef float4 f4;
typedef int4 i4;

// one 16-B load, 32-bit voffset + 64-bit SGPR base; volatile => pinned.
#define GLOAD(dst, voff, base) \
    asm volatile("global_load_dwordx4 %0, %1, %2" \
                 : "=v"(dst) : "v"(voff), "s"(base))

// wait for all but the newest NSTR outstanding loads; fence scheduler (rule 18)
#define WAITN(NSTR) do { \
    asm volatile("s_waitcnt vmcnt(" NSTR ")" ::: "memory"); \
    __builtin_amdgcn_sched_barrier(0); \
} while (0)

// Per-element u32 contribution: inter<<20 | sp<<10 | st.
// Bounds per LDS copy: 16 lanes x 32 elems = 512 max < 1023. Safe.
__device__ __forceinline__ unsigned int pack32(float p, float t) {
    unsigned int sp = (p != 0.0f) ? 1u : 0u;
    unsigned int st = (t != 0.0f) ? 1u : 0u;
    return ((sp & st) << 20) | (sp << 10) | st;
}

__device__ __forceinline__ void accum4(unsigned int (*s_cnt)[NSEG], int copy,
                                       f4 p, f4 t, i4 l) {
    atomicAdd(&s_cnt[copy][l.x], pack32(p.x, t.x));
    atomicAdd(&s_cnt[copy][l.y], pack32(p.y, t.y));
    atomicAdd(&s_cnt[copy][l.z], pack32(p.z, t.z));
    atomicAdd(&s_cnt[copy][l.w], pack32(p.w, t.w));
}

__global__ __launch_bounds__(THREADS, 4) void seg_count_kernel(
    const float* __restrict__ pred,
    const float* __restrict__ target,
    const int* __restrict__ labels,
    unsigned long long* __restrict__ part,   // [NSEG][NREP] packed u64, zeroed
    int n)
{
    __shared__ unsigned int s_cnt[NCOPY][NSEG];   // 4160 B
    const int tid = threadIdx.x;
    const int copy = tid >> 4;
    const int rep = (int)blockIdx.x & REP_MASK;

    for (int i = tid; i < NCOPY * NSEG; i += THREADS)
        ((unsigned int*)s_cnt)[i] = 0u;
    __syncthreads();

    const int n_vec = n >> 2;  // float4 groups
    const int chunk = (n_vec + (int)gridDim.x - 1) / (int)gridDim.x;
    const int base = blockIdx.x * chunk;
    const int end = min(base + chunk, n_vec);

    if (end - base == GP * THREADS) {
        // group g of this thread = byte offset vb + g*4096 in each array
        const unsigned int vb = (unsigned int)(base + tid) * 16u;
        f4 PA, PB;            // P[k] -> P{k%2}
        f4 TA, TB, TC;        // T[k] -> T{k%3}
        i4 LA, LB, LC, LD;    // L[k] -> L{k%4}

        // prologue: 6 in flight, spanning pages {0,4K,8K} per array
        GLOAD(LA, vb,           labels);
        GLOAD(LB, vb + 4096u,   labels);
        GLOAD(TA, vb,           target);
        GLOAD(LC, vb + 8192u,   labels);
        GLOAD(TB, vb + 4096u,   target);
        GLOAD(PA, vb,           pred);

        // g=0
        GLOAD(LD, vb + 12288u,  labels);
        GLOAD(TC, vb + 8192u,   target);
        GLOAD(PB, vb + 4096u,   pred);
        WAITN("3");  accum4(s_cnt, copy, PA, TA, LA);
        // g=1
        GLOAD(LA, vb + 16384u,  labels);
        GLOAD(TA, vb + 12288u,  target);
        GLOAD(PA, vb + 8192u,   pred);
        WAITN("3");  accum4(s_cnt, copy, PB, TB, LB);
        // g=2
        GLOAD(LB, vb + 20480u,  labels);
        GLOAD(TB, vb + 16384u,  target);
        GLOAD(PB, vb + 12288u,  pred);
        WAITN("3");  accum4(s_cnt, copy, PA, TC, LC);
        // g=3
        GLOAD(LC, vb + 24576u,  labels);
        GLOAD(TC, vb + 20480u,  target);
        GLOAD(PA, vb + 16384u,  pred);
        WAITN("3");  accum4(s_cnt, copy, PB, TA, LD);
        // g=4
        GLOAD(LD, vb + 28672u,  labels);
        GLOAD(TA, vb + 24576u,  target);
        GLOAD(PB, vb + 20480u,  pred);
        WAITN("3");  accum4(s_cnt, copy, PA, TB, LA);
        // g=5 (L exhausted)
        GLOAD(TB, vb + 28672u,  target);
        GLOAD(PA, vb + 24576u,  pred);
        WAITN("2");  accum4(s_cnt, copy, PB, TC, LB);
        // g=6 (T exhausted)
        GLOAD(PB, vb + 28672u,  pred);
        WAITN("1");  accum4(s_cnt, copy, PA, TA, LC);
        // g=7 (drain)
        WAITN("0");  accum4(s_cnt, copy, PB, TB, LD);
    } else {
        // generic fallback (not hit at n = 256^3 / 2048 blocks)
        const f4* __restrict__ p4 = (const f4*)pred;
        const f4* __restrict__ t4 = (const f4*)target;
        const i4* __restrict__ l4 = (const i4*)labels;
        for (int idx = base + tid; idx < end; idx += THREADS)
            accum4(s_cnt, copy, p4[idx], t4[idx], l4[idx]);
    }

    // scalar tail (n not divisible by 4): block 0 only
    if (blockIdx.x == 0) {
        for (int i = (n_vec << 2) + tid; i < n; i += THREADS)
            atomicAdd(&s_cnt[copy][labels[i]], pack32(pred[i], target[i]));
    }
    __syncthreads();

    // fold 16 u32 copies -> one packed u64 global atomic per segment into
    // this block's replica. Per-replica field bound: 32 blocks x 8192 =
    // 262k < 2^21. Safe.
    for (int s = tid; s < NSEG; s += THREADS) {
        unsigned long long in = 0, sp = 0, st = 0;
        #pragma unroll
        for (int c = 0; c < NCOPY; ++c) {
            unsigned int v = s_cnt[c][s];
            st += v & 0x3FFu;
            sp += (v >> 10) & 0x3FFu;
            in += v >> 20;
        }
        unsigned long long tot = (in << 42) | (sp << 21) | st;
        if (tot) atomicAdd(&part[s * NREP + rep], tot);
    }
}

__global__ __launch_bounds__(256) void dice_finalize_kernel(
    const unsigned long long* __restrict__ part,   // [NSEG][NREP]
    const int* __restrict__ nc_ptr,
    float* __restrict__ out)
{
    const int nc = *nc_ptr;          // 64
    const int tid = threadIdx.x;
    const int s = 1 + (tid >> 2);    // 4 threads per segment, 1..64
    const int q = tid & 3;

    unsigned long long acc = 0;
    const unsigned long long* row = part + s * NREP + q * 16;
    #pragma unroll
    for (int i = 0; i < 16; ++i) acc += row[i];
    acc += __shfl_xor(acc, 1);
    acc += __shfl_xor(acc, 2);

    __shared__ float s_dice[64];
    if (q == 0) {
        float in = (float)(acc >> 42);
        float sp = (float)((acc >> 21) & 0x1FFFFFull);
        float st = (float)(acc & 0x1FFFFFull);
        float uni = sp + st;
        float dice = (uni > 0.0f) ? (2.0f * in / uni) : 1.0f;
        s_dice[s - 1] = (s <= nc) ? dice : 0.0f;
    }
    __syncthreads();

    if (tid < 64) {
        float local = s_dice[tid];
        #pragma unroll
        for (int off = 32; off > 0; off >>= 1)
            local += __shfl_down(local, off);
        if (tid == 0) out[0] = 1.0f - local / (float)nc;
    }
}

extern "C" void kernel_launch(void* const* d_in, const int* in_sizes, int n_in,
                              void* d_out, int out_size, void* d_ws, size_t ws_size,
                              hipStream_t stream) {
    const float* pred   = (const float*)d_in[0];
    const float* target = (const float*)d_in[1];
    const int*   labels = (const int*)d_in[2];
    const int*   nc_ptr = (const int*)d_in[3];
    float* out = (float*)d_out;
    unsigned long long* part = (unsigned long long*)d_ws;

    const int n = in_sizes[0];

    hipMemsetAsync(d_ws, 0, NSEG * NREP * sizeof(unsigned long long), stream);

    seg_count_kernel<<<BLOCKS, THREADS, 0, stream>>>(
        pred, target, labels, part, n);
    dice_finalize_kernel<<<1, 256, 0, stream>>>(part, nc_ptr, out);
}